// Round 9
// baseline (118.926 us; speedup 1.0000x reference)
//
#include <hip/hip_runtime.h>

// Problem constants (fixed by the reference)
static constexpr int kB = 2;
static constexpr int kNV = 30000;
static constexpr int kD = 8;    // NDIRS
static constexpr int kR = 3;    // NRINGS
static constexpr int kC = 16;   // C
static constexpr int kF = 16;   // NF
static constexpr int NP = (kB * kNV) / 2;   // 30000 vertex-pairs
static constexpr int S  = 3840;             // pair stride == #waves (single-wave blocks)
static constexpr int NY4 = (kB * kNV * kD * kC) / 4;   // 1,920,000 float4 in y

typedef short short8  __attribute__((ext_vector_type(8)));   // 8 bf16
typedef float floatx4 __attribute__((ext_vector_type(4)));   // MFMA acc

// Per-wave LDS: two buffers of [patch 48x32B | center 16x64B(32 data + 32 zeros)]
static constexpr int CENT_OFS   = 1536;
static constexpr int BUF_STRIDE = 2560;

__device__ __forceinline__ unsigned bf16rne(float x) {
    unsigned u = __float_as_uint(x);
    return (u + 0x7fffu + ((u >> 16) & 1u)) >> 16;   // round-to-nearest-even
}

// Per-pair GEMM: D[16x16] = A[16x416] x B[416x16].
// K map: k = dd*48 + r*16 + c (conv, k<384); k = 384+c (center); 400..415 zero.
__global__ __launch_bounds__(64) void sgc_kernel(
    const float* __restrict__ y,          // (B, NV, NDIRS, C) fp32
    const int*   __restrict__ sync_field, // (B, NV, NRINGS, NDIRS, 3)
    const float* __restrict__ kern,       // (R, D, C, F) fp32
    const float* __restrict__ ck,         // (C, F) fp32
    const float* __restrict__ bias,       // (F,)
    float*       __restrict__ out)        // (B, NV, F)
{
    __shared__ __align__(16) char smem[2 * BUF_STRIDE];

    const int lane = threadIdx.x;        // single wave per block
    const int wid  = blockIdx.x;
    const int f    = lane & 15;          // MFMA col / feature
    const int q    = lane >> 4;          // MFMA k-quad
    const int mvtx = (lane >> 3) & 1;    // A-row vertex-in-pair
    const int md   = lane & 7;           // A-row direction

    // ---- L3 warm phase: stream a disjoint 8KB slice of y (coalesced). ----
    // Harness re-poisons 268MB of ws each launch -> L3 is cold; the random
    // gathers below hit HBM at ~2.3 TB/s (random-64B wall). Streaming all of
    // y into L3 first (~5us) converts those misses into L3 hits.
    {
        float4 w[8];
#pragma unroll
        for (int i = 0; i < 8; ++i) {
            int idx = wid * 512 + i * 64 + lane;
            idx = idx < NY4 ? idx : NY4 - 1;
            w[i] = reinterpret_cast<const float4*>(y)[idx];
        }
#pragma unroll
        for (int i = 0; i < 8; ++i)
            __asm__ __volatile__("" :: "v"(w[i].x), "v"(w[i].y),
                                       "v"(w[i].z), "v"(w[i].w));
    }

    // ---- one-time: zero the 32B upper half of all 16 center slots, both bufs
    {
        const int buf = lane >> 5, z = lane & 31;
        const int ofs = buf * BUF_STRIDE + CENT_OFS + (z >> 1) * 64 + 32 + (z & 1) * 16;
        *(uint4*)(smem + ofs) = make_uint4(0u, 0u, 0u, 0u);
    }

    // ---- per-lane chunk geometry + B-fragments (once per wave) ----
    int aOfs[12];
    short8 bfrag[13];
#pragma unroll
    for (int kk = 0; kk < 12; ++kk) {
        const int g   = kk * 4 + q;
        const int dd  = (g * 43) >> 8;       // g/6 for g<48
        const int rem = g - dd * 6;
        const int r   = rem >> 1;
        const int ch  = rem & 1;
        const int rot = (md + dd) & 7;
        aOfs[kk] = ((mvtx * 3 + r) * 8 + rot) * 32 + ch * 16;   // bytes
        const int be = ((r * 8 + dd) * 16 + ch * 8) * 16 + f;
        union { unsigned u[4]; short8 v; } t;
#pragma unroll
        for (int j = 0; j < 4; ++j) {
            const float a = kern[be + (2 * j) * 16];
            const float b = kern[be + (2 * j + 1) * 16];
            t.u[j] = bf16rne(a) | (bf16rne(b) << 16);
        }
        bfrag[kk] = t.v;
    }
    {   // center B-chunk: q=0 -> ck c0-7, q=1 -> c8-15, q>=2 -> zeros
        union { unsigned u[4]; short8 v; } t;
        if (q < 2) {
#pragma unroll
            for (int j = 0; j < 4; ++j) {
                const float a = ck[(q * 8 + 2 * j) * 16 + f];
                const float b = ck[(q * 8 + 2 * j + 1) * 16 + f];
                t.u[j] = bf16rne(a) | (bf16rne(b) << 16);
            }
        } else {
            t.u[0] = t.u[1] = t.u[2] = t.u[3] = 0u;
        }
        bfrag[12] = t.v;
    }
    const float biasv = bias[f];

    // ---- roles: lanes 0..47 gather patch entry `lane`; 48..63 center row m --
    const bool isPatch = lane < 48;
    const int  cenElem = (lane & 15) * 16;   // center row m -> elem offset in pair

    auto cl = [](int v) { return v < NP ? v : NP - 1; };

    int t0 = 0, t1 = 0, t2 = 0;   // sf triple for the NEXT patch issue
    float4 A0, A1, A2, A3, B0, B1, B2, B3;

#define SF_PRE(cc) do { if (isPatch) { \
        const int* s_ = sync_field + (size_t)((cc) * 48 + lane) * 3; \
        t0 = s_[0]; t1 = s_[1]; t2 = s_[2]; } } while (0)

#define ISSUE_G(Rv, cc) do { \
        const float4* gp_; \
        if (isPatch) \
            gp_ = reinterpret_cast<const float4*>( \
                y + ((t0 * kNV + t1) * kD + t2) * kC); \
        else \
            gp_ = reinterpret_cast<const float4*>( \
                y + (size_t)(cc) * 256 + cenElem); \
        Rv##0 = gp_[0]; Rv##1 = gp_[1]; Rv##2 = gp_[2]; Rv##3 = gp_[3]; \
    } while (0)

#define STAGE(Rv, bufbase) do { \
        unsigned wu_[8]; \
        const float4 gg_[4] = { Rv##0, Rv##1, Rv##2, Rv##3 }; \
        _Pragma("unroll") \
        for (int i_ = 0; i_ < 4; ++i_) { \
            wu_[2 * i_]     = bf16rne(gg_[i_].x) | (bf16rne(gg_[i_].y) << 16); \
            wu_[2 * i_ + 1] = bf16rne(gg_[i_].z) | (bf16rne(gg_[i_].w) << 16); \
        } \
        char* wp_ = (bufbase) + (isPatch ? lane * 32 : CENT_OFS + cenElem * 4); \
        *(uint4*)(wp_)      = make_uint4(wu_[0], wu_[1], wu_[2], wu_[3]); \
        *(uint4*)(wp_ + 16) = make_uint4(wu_[4], wu_[5], wu_[6], wu_[7]); \
    } while (0)

#define DRAIN do { \
        __asm__ __volatile__("" ::: "memory"); \
        __builtin_amdgcn_s_waitcnt(0xC07F); /* lgkmcnt(0) only */ \
        __asm__ __volatile__("" ::: "memory"); \
    } while (0)

#define COMPUTE_STORE(bufbase, pp) do { \
        floatx4 acc0 = { biasv, biasv, biasv, biasv }; \
        floatx4 acc1 = { 0.f, 0.f, 0.f, 0.f }; \
        _Pragma("unroll") \
        for (int kk_ = 0; kk_ < 12; kk_ += 2) { \
            const short8 a0_ = *(const short8*)((bufbase) + aOfs[kk_]); \
            const short8 a1_ = *(const short8*)((bufbase) + aOfs[kk_ + 1]); \
            acc0 = __builtin_amdgcn_mfma_f32_16x16x32_bf16(a0_, bfrag[kk_], acc0, 0, 0, 0); \
            acc1 = __builtin_amdgcn_mfma_f32_16x16x32_bf16(a1_, bfrag[kk_ + 1], acc1, 0, 0, 0); \
        } \
        { \
            const short8 ac_ = *(const short8*)((bufbase) + CENT_OFS \
                                                + (lane & 15) * 64 + q * 16); \
            acc0 = __builtin_amdgcn_mfma_f32_16x16x32_bf16(ac_, bfrag[12], acc0, 0, 0, 0); \
        } \
        float mx = fmaxf(fmaxf(acc0[0] + acc1[0], acc0[1] + acc1[1]), \
                         fmaxf(acc0[2] + acc1[2], acc0[3] + acc1[3])); \
        mx = fmaxf(mx, 0.0f); \
        mx = fmaxf(mx, __shfl_xor(mx, 16, 64)); \
        if (((lane >> 4) & 1) == 0) \
            out[(2 * (pp) + (lane >> 5)) * kF + f] = mx; \
    } while (0)

    // ---- prologue: LDS0 <- p; B in flight (p+S); A in flight (p+2S);
    //      t = sf(p+3S). Steady-state MLP = 2 gather batches / lane.
    int p = wid;                       // wid < 3840 <= NP
    SF_PRE(p);
    ISSUE_G(A, p);
    SF_PRE(cl(p + S));
    ISSUE_G(B, cl(p + S));
    SF_PRE(cl(p + 2 * S));
    STAGE(A, smem);                    // waits A only; B stays in flight
    ISSUE_G(A, cl(p + 2 * S));
    SF_PRE(cl(p + 3 * S));

    for (;;) {
        // even step: compute buf0 (pair p); stage B (p+S) -> buf1
        STAGE(B, smem + BUF_STRIDE);   // waits B; A stays in flight
        ISSUE_G(B, cl(p + 3 * S));
        SF_PRE(cl(p + 4 * S));
        DRAIN;
        COMPUTE_STORE(smem, p);
        p += S; if (p >= NP) break;

        // odd step: compute buf1 (pair p); stage A (p+S) -> buf0
        STAGE(A, smem);                // waits A; B stays in flight
        ISSUE_G(A, cl(p + 3 * S));
        SF_PRE(cl(p + 4 * S));
        DRAIN;
        COMPUTE_STORE(smem + BUF_STRIDE, p);
        p += S; if (p >= NP) break;
    }

#undef SF_PRE
#undef ISSUE_G
#undef STAGE
#undef DRAIN
#undef COMPUTE_STORE
}

extern "C" void kernel_launch(void* const* d_in, const int* in_sizes, int n_in,
                              void* d_out, int out_size, void* d_ws, size_t ws_size,
                              hipStream_t stream) {
    const float* y    = reinterpret_cast<const float*>(d_in[0]);
    const int*   sf   = reinterpret_cast<const int*>(d_in[1]);
    const float* kern = reinterpret_cast<const float*>(d_in[2]);
    const float* ck   = reinterpret_cast<const float*>(d_in[3]);
    const float* bias = reinterpret_cast<const float*>(d_in[4]);
    float* out = reinterpret_cast<float*>(d_out);

    sgc_kernel<<<S, 64, 0, stream>>>(y, sf, kern, ck, bias, out);
}

// Round 10
// 113.120 us; speedup vs baseline: 1.0513x; 1.0513x over previous
//
#include <hip/hip_runtime.h>

// Problem constants (fixed by the reference)
static constexpr int kB = 2;
static constexpr int kNV = 30000;
static constexpr int kD = 8;    // NDIRS
static constexpr int kR = 3;    // NRINGS
static constexpr int kC = 16;   // C
static constexpr int kF = 16;   // NF
static constexpr int NP = (kB * kNV) / 2;   // 30000 vertex-pairs
static constexpr int S  = 3840;             // pair stride == #waves (single-wave blocks)

typedef short short8  __attribute__((ext_vector_type(8)));   // 8 bf16
typedef float floatx4 __attribute__((ext_vector_type(4)));   // MFMA acc

// Per-wave LDS: two buffers of [patch 48x32B | center 16x64B(32 data + 32 zeros)]
static constexpr int CENT_OFS   = 1536;
static constexpr int BUF_STRIDE = 2560;

__device__ __forceinline__ unsigned bf16rne(float x) {
    unsigned u = __float_as_uint(x);
    return (u + 0x7fffu + ((u >> 16) & 1u)) >> 16;   // round-to-nearest-even
}

// Per-pair GEMM: D[16x16] = A[16x416] x B[416x16].
// K map: k = dd*48 + r*16 + c (conv, k<384); k = 384+c (center); 400..415 zero.
// Gather: 4 consecutive lanes split one 64B entry (16B each) so the TCP can
// coalesce same-line lane requests within one instruction — 48 64B
// transactions per iteration instead of 192 scattered 16B ones.
__global__ __launch_bounds__(64) void sgc_kernel(
    const float* __restrict__ y,          // (B, NV, NDIRS, C) fp32
    const int*   __restrict__ sync_field, // (B, NV, NRINGS, NDIRS, 3)
    const float* __restrict__ kern,       // (R, D, C, F) fp32
    const float* __restrict__ ck,         // (C, F) fp32
    const float* __restrict__ bias,       // (F,)
    float*       __restrict__ out)        // (B, NV, F)
{
    __shared__ __align__(16) char smem[2 * BUF_STRIDE];

    const int lane = threadIdx.x;        // single wave per block
    const int wid  = blockIdx.x;
    const int f    = lane & 15;          // MFMA col / feature
    const int q    = lane >> 4;          // MFMA k-quad
    const int mvtx = (lane >> 3) & 1;    // A-row vertex-in-pair
    const int md   = lane & 7;           // A-row direction
    const int eSub = lane >> 2;          // entry-in-group (0..15)
    const int iq   = lane & 3;           // 16B quad within the 64B entry

    // ---- one-time: zero the 32B upper half of all 16 center slots, both bufs
    {
        const int buf = lane >> 5, z = lane & 31;
        const int ofs = buf * BUF_STRIDE + CENT_OFS + (z >> 1) * 64 + 32 + (z & 1) * 16;
        *(uint4*)(smem + ofs) = make_uint4(0u, 0u, 0u, 0u);
    }

    // ---- per-lane chunk geometry + B-fragments (once per wave) ----
    int aOfs[12];
    short8 bfrag[13];
#pragma unroll
    for (int kk = 0; kk < 12; ++kk) {
        const int g   = kk * 4 + q;
        const int dd  = (g * 43) >> 8;       // g/6 for g<48
        const int rem = g - dd * 6;
        const int r   = rem >> 1;
        const int ch  = rem & 1;
        const int rot = (md + dd) & 7;
        aOfs[kk] = ((mvtx * 3 + r) * 8 + rot) * 32 + ch * 16;   // bytes
        const int be = ((r * 8 + dd) * 16 + ch * 8) * 16 + f;
        union { unsigned u[4]; short8 v; } t;
#pragma unroll
        for (int j = 0; j < 4; ++j) {
            const float a = kern[be + (2 * j) * 16];
            const float b = kern[be + (2 * j + 1) * 16];
            t.u[j] = bf16rne(a) | (bf16rne(b) << 16);
        }
        bfrag[kk] = t.v;
    }
    {   // center B-chunk: q=0 -> ck c0-7, q=1 -> c8-15, q>=2 -> zeros
        union { unsigned u[4]; short8 v; } t;
        if (q < 2) {
#pragma unroll
            for (int j = 0; j < 4; ++j) {
                const float a = ck[(q * 8 + 2 * j) * 16 + f];
                const float b = ck[(q * 8 + 2 * j + 1) * 16 + f];
                t.u[j] = bf16rne(a) | (bf16rne(b) << 16);
            }
        } else {
            t.u[0] = t.u[1] = t.u[2] = t.u[3] = 0u;
        }
        bfrag[12] = t.v;
    }
    const float biasv = bias[f];

    auto cl = [](int v) { return v < NP ? v : NP - 1; };

    // sf triples for the NEXT patch issue (per group g=0..2; entry = g*16+eSub)
    int tA[3], tB[3], tC[3];
    float4 A0, A1, A2, Ac, B0, B1, B2, Bc;

#define SF_PRE(cc) do { \
        const int base_ = (cc) * 48; \
        _Pragma("unroll") \
        for (int g_ = 0; g_ < 3; ++g_) { \
            const int* s_ = sync_field + (size_t)(base_ + g_ * 16 + eSub) * 3; \
            tA[g_] = s_[0]; tB[g_] = s_[1]; tC[g_] = s_[2]; \
        } \
    } while (0)

#define ISSUE_G(Rv, cc) do { \
        { const float4* gp_ = reinterpret_cast<const float4*>( \
              y + ((tA[0] * kNV + tB[0]) * kD + tC[0]) * kC) + iq; Rv##0 = *gp_; } \
        { const float4* gp_ = reinterpret_cast<const float4*>( \
              y + ((tA[1] * kNV + tB[1]) * kD + tC[1]) * kC) + iq; Rv##1 = *gp_; } \
        { const float4* gp_ = reinterpret_cast<const float4*>( \
              y + ((tA[2] * kNV + tB[2]) * kD + tC[2]) * kC) + iq; Rv##2 = *gp_; } \
        Rv##c = reinterpret_cast<const float4*>(y + (size_t)(cc) * 256)[lane]; \
    } while (0)

#define STAGE(Rv, bufbase) do { \
        const float4 gg_[3] = { Rv##0, Rv##1, Rv##2 }; \
        _Pragma("unroll") \
        for (int g_ = 0; g_ < 3; ++g_) { \
            uint2 w_; \
            w_.x = bf16rne(gg_[g_].x) | (bf16rne(gg_[g_].y) << 16); \
            w_.y = bf16rne(gg_[g_].z) | (bf16rne(gg_[g_].w) << 16); \
            *(uint2*)((bufbase) + g_ * 512 + lane * 8) = w_; \
        } \
        { \
            uint2 w_; \
            w_.x = bf16rne(Rv##c.x) | (bf16rne(Rv##c.y) << 16); \
            w_.y = bf16rne(Rv##c.z) | (bf16rne(Rv##c.w) << 16); \
            *(uint2*)((bufbase) + CENT_OFS + eSub * 64 + iq * 8) = w_; \
        } \
    } while (0)

#define DRAIN do { \
        __asm__ __volatile__("" ::: "memory"); \
        __builtin_amdgcn_s_waitcnt(0xC07F); /* lgkmcnt(0) only */ \
        __asm__ __volatile__("" ::: "memory"); \
    } while (0)

#define COMPUTE_STORE(bufbase, pp) do { \
        floatx4 acc0 = { biasv, biasv, biasv, biasv }; \
        floatx4 acc1 = { 0.f, 0.f, 0.f, 0.f }; \
        _Pragma("unroll") \
        for (int kk_ = 0; kk_ < 12; kk_ += 2) { \
            const short8 a0_ = *(const short8*)((bufbase) + aOfs[kk_]); \
            const short8 a1_ = *(const short8*)((bufbase) + aOfs[kk_ + 1]); \
            acc0 = __builtin_amdgcn_mfma_f32_16x16x32_bf16(a0_, bfrag[kk_], acc0, 0, 0, 0); \
            acc1 = __builtin_amdgcn_mfma_f32_16x16x32_bf16(a1_, bfrag[kk_ + 1], acc1, 0, 0, 0); \
        } \
        { \
            const short8 ac_ = *(const short8*)((bufbase) + CENT_OFS \
                                                + (lane & 15) * 64 + q * 16); \
            acc0 = __builtin_amdgcn_mfma_f32_16x16x32_bf16(ac_, bfrag[12], acc0, 0, 0, 0); \
        } \
        float mx = fmaxf(fmaxf(acc0[0] + acc1[0], acc0[1] + acc1[1]), \
                         fmaxf(acc0[2] + acc1[2], acc0[3] + acc1[3])); \
        mx = fmaxf(mx, 0.0f); \
        mx = fmaxf(mx, __shfl_xor(mx, 16, 64)); \
        if (((lane >> 4) & 1) == 0) \
            out[(2 * (pp) + (lane >> 5)) * kF + f] = mx; \
    } while (0)

    // ---- prologue: LDS0 <- p; B in flight (p+S); A in flight (p+2S);
    //      t = sf(p+3S). Steady-state MLP = 2 gather batches / lane.
    int p = wid;                       // wid < 3840 <= NP
    SF_PRE(p);
    ISSUE_G(A, p);
    SF_PRE(cl(p + S));
    ISSUE_G(B, cl(p + S));
    SF_PRE(cl(p + 2 * S));
    STAGE(A, smem);                    // waits A only; B stays in flight
    ISSUE_G(A, cl(p + 2 * S));
    SF_PRE(cl(p + 3 * S));

    for (;;) {
        // even step: compute buf0 (pair p); stage B (p+S) -> buf1
        STAGE(B, smem + BUF_STRIDE);   // waits B; A stays in flight
        ISSUE_G(B, cl(p + 3 * S));
        SF_PRE(cl(p + 4 * S));
        DRAIN;
        COMPUTE_STORE(smem, p);
        p += S; if (p >= NP) break;

        // odd step: compute buf1 (pair p); stage A (p+S) -> buf0
        STAGE(A, smem);                // waits A; B stays in flight
        ISSUE_G(A, cl(p + 3 * S));
        SF_PRE(cl(p + 4 * S));
        DRAIN;
        COMPUTE_STORE(smem + BUF_STRIDE, p);
        p += S; if (p >= NP) break;
    }

#undef SF_PRE
#undef ISSUE_G
#undef STAGE
#undef DRAIN
#undef COMPUTE_STORE
}

extern "C" void kernel_launch(void* const* d_in, const int* in_sizes, int n_in,
                              void* d_out, int out_size, void* d_ws, size_t ws_size,
                              hipStream_t stream) {
    const float* y    = reinterpret_cast<const float*>(d_in[0]);
    const int*   sf   = reinterpret_cast<const int*>(d_in[1]);
    const float* kern = reinterpret_cast<const float*>(d_in[2]);
    const float* ck   = reinterpret_cast<const float*>(d_in[3]);
    const float* bias = reinterpret_cast<const float*>(d_in[4]);
    float* out = reinterpret_cast<float*>(d_out);

    sgc_kernel<<<S, 64, 0, stream>>>(y, sf, kern, ck, bias, out);
}